// Round 7
// baseline (80.397 us; speedup 1.0000x reference)
//
#include <hip/hip_runtime.h>
#include <math.h>

#define M_CHECKS 63
#define N_CODE   127
#define ROW_W    8
#define BATCH    4096
#define NITER    5
#define BIGF     1e10f
#define MAXD     16   // max column degree; proven sufficient (rounds 3-6 passed with clamp@16)

// Flooding NMS decoder, atomic-free, bank-conflict-free, and waitcnt-free in
// the main loop. One wave = one batch row.
//   check phase : lane i (<63) gathers its 8 column values from LDS cur[],
//                 computes (min1,min2,sign_prod), writes finished per-edge
//                 contributions cv = norm*upd*sprod*s to cvals[slot][col].
//   column phase: lane owns cols {lane, lane+64}; interleaved strip sum
//                 cvals[e*128+j0] / cvals[e*128+j1] — byte offsets e*512 and
//                 e*512+256 merge into ds_read2st64_b32 (offsets 2e, 2e+1),
//                 bank = j%32 => conflict-free.
// NO s_waitcnt in the loop: a wave's DS ops execute in order on the LDS pipe
// (lgkmcnt for DS decrements in issue order), so scatter-write -> strip-read
// and cur-write -> next-iter gather are ordered in hardware. The empty
// memory-clobber asm + sched_barrier(0) only pin the COMPILER's program
// order (zero instructions emitted). Result-use waits are inserted by the
// compiler per-VGPR as usual.
__launch_bounds__(256, 4)
__global__ void nms_decode(const float* __restrict__ soft,
                           const int*   __restrict__ labels,
                           const int*   __restrict__ H,
                           const float* __restrict__ normalizor,
                           float*       __restrict__ out) {
    __shared__ float cur[4][128];             // per-wave row state
    __shared__ float cvals[4][MAXD][128];     // per-wave slot-major edge contributions (32 KB)
    __shared__ int   sidx[M_CHECKS * ROW_W];  // check -> column
    __shared__ int   sslot[M_CHECKS * ROW_W]; // check -> slot within column
    __shared__ int   cnt[128];                // column degrees (build only)

    const int tid  = threadIdx.x;
    const int w    = tid >> 6;
    const int lane = tid & 63;
    const int row  = blockIdx.x * 4 + w;

    // zero cvals (padding slots must read as 0.0 forever) + cnt
    {
        float4* cv4 = (float4*)cvals;
        #pragma unroll
        for (int t = 0; t < (4 * MAXD * 128) / 4 / 256; ++t)
            cv4[tid + t * 256] = make_float4(0.f, 0.f, 0.f, 0.f);
        if (tid < 128) cnt[tid] = 0;
    }

    // ---- build check->column table (ballot compaction of dense H) ----
    {
        const unsigned long long below =
            (lane == 0) ? 0ull : ((~0ull) >> (64 - lane));
        for (int i = w; i < M_CHECKS; i += 4) {
            const int c0 = lane;
            const int c1 = lane + 64;
            const int b0 = (H[i * N_CODE + c0] != 0) ? 1 : 0;
            const int b1 = (c1 < N_CODE) ? ((H[i * N_CODE + c1] != 0) ? 1 : 0) : 0;
            unsigned long long m0 = __ballot(b0);
            unsigned long long m1 = __ballot(b1);
            if (b0) {
                int pos = __popcll(m0 & below);
                if (pos < ROW_W) sidx[i * ROW_W + pos] = c0;
            }
            if (b1) {
                int pos = __popcll(m0) + __popcll(m1 & below);
                if (pos < ROW_W) sidx[i * ROW_W + pos] = c1;
            }
        }
    }
    __syncthreads();   // sidx + zeroed cnt/cvals visible

    // ---- assign per-edge slots (wave 0; native integer LDS atomics) ----
    if (w == 0 && lane < M_CHECKS) {
        #pragma unroll
        for (int p = 0; p < ROW_W; ++p) {
            int c = sidx[lane * ROW_W + p];
            sslot[lane * ROW_W + p] = atomicAdd(&cnt[c], 1);   // < MAXD, proven
        }
    }
    __syncthreads();   // sslot visible to all waves

    const float norm = log1pf(expf(normalizor[0]));  // softplus
    float* outLabels = out + (size_t)(NITER + 1) * BATCH * N_CODE;
    float* const cvw = &cvals[w][0][0];

    // ---- hoist per-check edge tables into registers (conflicts paid once) ----
    int ec[ROW_W];     // column of edge p
    int widx[ROW_W];   // slot*128 + column  (cvals write offset)
    if (lane < M_CHECKS) {
        #pragma unroll
        for (int p = 0; p < ROW_W; ++p) {
            ec[p]   = sidx[lane * ROW_W + p];
            widx[p] = sslot[lane * ROW_W + p] * 128 + ec[p];
        }
    }

    // ---- load state + emit outs[0] and labels ----
    const int j0 = lane;
    const int j1 = lane + 64;           // lane 63 -> 127: pad column, never stored
    float x0, x1 = 0.0f;
    {
        const size_t base = (size_t)row * N_CODE;
        x0 = soft[base + j0];
        cur[w][j0] = x0;
        out[base + j0] = x0;                                   // outs[0]
        outLabels[base + j0] = (float)labels[base + j0];       // labels as 0.0/1.0
        if (lane < 63) {
            x1 = soft[base + j1];
            cur[w][j1] = x1;
            out[base + j1] = x1;
            outLabels[base + j1] = (float)labels[base + j1];
        }
    }
    // cur writes -> first gather: in-order DS pipe handles the hazard; just
    // stop the compiler from hoisting the gathers above the writes.
    asm volatile("" ::: "memory");
    __builtin_amdgcn_sched_barrier(0);

    for (int it = 0; it < NITER; ++it) {
        // ---- check phase ----
        if (lane < M_CHECKS) {
            float v[ROW_W];
            #pragma unroll
            for (int p = 0; p < ROW_W; ++p) v[p] = cur[w][ec[p]];

            float m1 = BIGF, m2 = BIGF, sprod = 1.0f;
            #pragma unroll
            for (int p = 0; p < ROW_W; ++p) {
                float x = v[p];
                float s = (x > 0.0f) ? 1.0f : ((x < 0.0f) ? -1.0f : 0.0f);
                sprod *= s;
                float av   = fabsf(x);
                float proc = (av == 0.0f) ? BIGF : av;          // zeros -> BIG (ref rule)
                if (proc < m1) { m2 = m1; m1 = proc; }
                else if (proc < m2) { m2 = proc; }
            }
            const float nsp = norm * sprod;
            #pragma unroll
            for (int p = 0; p < ROW_W; ++p) {
                float x   = v[p];
                float s   = (x > 0.0f) ? 1.0f : ((x < 0.0f) ? -1.0f : 0.0f);
                float av  = fabsf(x);
                float upd = (av == m1) ? m2 : m1;               // exact-equality rule
                cvw[widx[p]] = nsp * upd * s;                   // finished contribution
            }
        }
        // scatter-writes -> strip-reads: ordered by the in-order DS pipe.
        asm volatile("" ::: "memory");
        __builtin_amdgcn_sched_barrier(0);

        // ---- column phase: interleaved conflict-free strip sums ----
        // cvw[e*128+j0] (byte e*512) and cvw[e*128+j1] (byte e*512+256) merge
        // into one ds_read2st64_b32 per e (offsets 2e, 2e+1).
        float acc0 = 0.0f, acc1 = 0.0f;
        #pragma unroll
        for (int e = 0; e < MAXD; ++e) {
            acc0 += cvw[e * 128 + j0];
            acc1 += cvw[e * 128 + j1];
        }
        x0 += acc0;
        x1 += acc1;

        cur[w][j0] = x0;
        if (lane < 63) cur[w][j1] = x1;

        const size_t obase = (size_t)(it + 1) * BATCH * N_CODE + (size_t)row * N_CODE;
        out[obase + j0] = x0;
        if (lane < 63) out[obase + j1] = x1;

        // cur-writes -> next-iter gathers: ordered by the in-order DS pipe.
        asm volatile("" ::: "memory");
        __builtin_amdgcn_sched_barrier(0);
    }
}

extern "C" void kernel_launch(void* const* d_in, const int* in_sizes, int n_in,
                              void* d_out, int out_size, void* d_ws, size_t ws_size,
                              hipStream_t stream) {
    const float* soft       = (const float*)d_in[0];
    const int*   labels     = (const int*)d_in[1];
    const int*   H          = (const int*)d_in[2];
    const float* normalizor = (const float*)d_in[3];
    float*       out        = (float*)d_out;

    nms_decode<<<BATCH / 4, 256, 0, stream>>>(soft, labels, H, normalizor, out);
}

// Round 9
// 79.556 us; speedup vs baseline: 1.0106x; 1.0106x over previous
//
#include <hip/hip_runtime.h>
#include <math.h>

#define M_CHECKS 63
#define N_CODE   127
#define ROW_W    8
#define BATCH    4096
#define NITER    5
#define BIGF     1e10f
#define MAXD     16   // max column degree bound; proven sufficient (rounds 3-7 passed)

// Flooding NMS decoder. One wave = one batch row.
//   check phase : lane i (<63) gathers its 8 column values from LDS cur[],
//                 computes (min1,min2,sign_prod), writes finished per-edge
//                 contributions cv = norm*upd*sprod*s into cvals.
//   column phase: lane owns cols {lane, lane+64}; strip-sum over slots.
// Round-8 changes (DS-pipe reduction, the dominant cost):
//   * cvals layout [slot/2][128][2]: slot pair (2e,2e+1) of column j are
//     ADJACENT words -> strip read is a true 1-address ds_read_b64
//     (read2st64 was 2 addresses = 2x b32 cost; that's why round 7 was null).
//     Banks: word (2j+m)%32 -> 4 words/bank uniform = conflict-free.
//   * strip loop bounded by the block's real max column degree (wave-uniform
//     smax from cnt[], expected ~9-10 vs 16) -> skips always-zero slots.
//   * cur[j0],cur[j1] written unconditionally (j1=127 is a pad column:
//     never gathered, never stored) -> merges to one write2st64.
__launch_bounds__(256, 4)
__global__ void nms_decode(const float* __restrict__ soft,
                           const int*   __restrict__ labels,
                           const int*   __restrict__ H,
                           const float* __restrict__ normalizor,
                           float*       __restrict__ out) {
    __shared__ float cur[4][128];              // per-wave row state
    __shared__ float cvals[4][MAXD / 2][128][2]; // per-wave paired-slot edge values (32 KB)
    __shared__ int   sidx[M_CHECKS * ROW_W];   // check -> column
    __shared__ int   sslot[M_CHECKS * ROW_W];  // check -> slot within column
    __shared__ int   cnt[128];                 // column degrees

    const int tid  = threadIdx.x;
    const int w    = tid >> 6;
    const int lane = tid & 63;
    const int row  = blockIdx.x * 4 + w;

    // zero cvals (never-written slots must read 0.0 forever) + cnt
    {
        float4* cv4 = (float4*)cvals;
        #pragma unroll
        for (int t = 0; t < (4 * MAXD * 128) / 4 / 256; ++t)
            cv4[tid + t * 256] = make_float4(0.f, 0.f, 0.f, 0.f);
        if (tid < 128) cnt[tid] = 0;
    }

    // ---- build check->column table (ballot compaction of dense H) ----
    {
        const unsigned long long below =
            (lane == 0) ? 0ull : ((~0ull) >> (64 - lane));
        for (int i = w; i < M_CHECKS; i += 4) {
            const int c0 = lane;
            const int c1 = lane + 64;
            const int b0 = (H[i * N_CODE + c0] != 0) ? 1 : 0;
            const int b1 = (c1 < N_CODE) ? ((H[i * N_CODE + c1] != 0) ? 1 : 0) : 0;
            unsigned long long m0 = __ballot(b0);
            unsigned long long m1 = __ballot(b1);
            if (b0) {
                int pos = __popcll(m0 & below);
                if (pos < ROW_W) sidx[i * ROW_W + pos] = c0;
            }
            if (b1) {
                int pos = __popcll(m0) + __popcll(m1 & below);
                if (pos < ROW_W) sidx[i * ROW_W + pos] = c1;
            }
        }
    }
    __syncthreads();   // sidx + zeroed cnt/cvals visible

    // ---- assign per-edge slots (wave 0; native integer LDS atomics) ----
    if (w == 0 && lane < M_CHECKS) {
        #pragma unroll
        for (int p = 0; p < ROW_W; ++p) {
            int c = sidx[lane * ROW_W + p];
            sslot[lane * ROW_W + p] = atomicAdd(&cnt[c], 1);   // < MAXD, proven
        }
    }
    __syncthreads();   // sslot + final cnt visible to all waves

    // ---- wave-uniform max column degree -> strip pair count ----
    int dmax = max(cnt[lane], cnt[lane + 64]);     // cnt[127] == 0 (pad)
    #pragma unroll
    for (int off = 32; off; off >>= 1)
        dmax = max(dmax, __shfl_xor(dmax, off, 64));
    const int spairs = min((dmax + 1) >> 1, MAXD / 2);  // b64 pairs to sum

    const float norm = log1pf(expf(normalizor[0]));  // softplus
    float* outLabels = out + (size_t)(NITER + 1) * BATCH * N_CODE;
    float* const cvw = &cvals[w][0][0][0];

    // ---- hoist per-check edge tables into registers (conflicts paid once) ----
    int ec[ROW_W];     // column of edge p
    int widx[ROW_W];   // word offset in paired layout: (s>>1)*256 + 2c + (s&1)
    if (lane < M_CHECKS) {
        #pragma unroll
        for (int p = 0; p < ROW_W; ++p) {
            int c   = sidx[lane * ROW_W + p];
            int s   = min(sslot[lane * ROW_W + p], MAXD - 1);
            ec[p]   = c;
            widx[p] = (s >> 1) * 256 + 2 * c + (s & 1);
        }
    }

    // ---- load state + emit outs[0] and labels ----
    const int j0 = lane;
    const int j1 = lane + 64;           // lane 63 -> 127: pad column, never stored
    float x0, x1 = 0.0f;
    {
        const size_t base = (size_t)row * N_CODE;
        x0 = soft[base + j0];
        cur[w][j0] = x0;
        out[base + j0] = x0;                                   // outs[0]
        outLabels[base + j0] = (float)labels[base + j0];       // labels as 0.0/1.0
        if (lane < 63) {
            x1 = soft[base + j1];
            cur[w][j1] = x1;
            out[base + j1] = x1;
            outLabels[base + j1] = (float)labels[base + j1];
        }
    }
    // cur writes -> first gather: in-order DS pipe orders the hazard; pin
    // compiler program order only (zero instructions).
    asm volatile("" ::: "memory");
    __builtin_amdgcn_sched_barrier(0);

    for (int it = 0; it < NITER; ++it) {
        // ---- check phase ----
        if (lane < M_CHECKS) {
            float v[ROW_W];
            #pragma unroll
            for (int p = 0; p < ROW_W; ++p) v[p] = cur[w][ec[p]];

            float m1 = BIGF, m2 = BIGF, sprod = 1.0f;
            #pragma unroll
            for (int p = 0; p < ROW_W; ++p) {
                float x = v[p];
                float s = (x > 0.0f) ? 1.0f : ((x < 0.0f) ? -1.0f : 0.0f);
                sprod *= s;
                float av   = fabsf(x);
                float proc = (av == 0.0f) ? BIGF : av;          // zeros -> BIG (ref rule)
                if (proc < m1) { m2 = m1; m1 = proc; }
                else if (proc < m2) { m2 = proc; }
            }
            const float nsp = norm * sprod;
            #pragma unroll
            for (int p = 0; p < ROW_W; ++p) {
                float x   = v[p];
                float s   = (x > 0.0f) ? 1.0f : ((x < 0.0f) ? -1.0f : 0.0f);
                float av  = fabsf(x);
                float upd = (av == m1) ? m2 : m1;               // exact-equality rule
                cvw[widx[p]] = nsp * upd * s;                   // finished contribution
            }
        }
        // scatter-writes -> strip-reads: ordered by the in-order DS pipe.
        asm volatile("" ::: "memory");
        __builtin_amdgcn_sched_barrier(0);

        // ---- column phase: b64 strip sums over live slot pairs only ----
        const float2* cv2 = (const float2*)cvw;
        float acc0 = 0.0f, acc1 = 0.0f;
        for (int e = 0; e < spairs; ++e) {
            float2 a = cv2[e * 128 + j0];   // 1-address b64, conflict-free
            float2 b = cv2[e * 128 + j1];
            acc0 += a.x + a.y;
            acc1 += b.x + b.y;
        }
        x0 += acc0;
        x1 += acc1;

        cur[w][j0] = x0;     // unconditional pair: merges to write2st64
        cur[w][j1] = x1;     // j1=127 is a harmless pad slot for lane 63

        const size_t obase = (size_t)(it + 1) * BATCH * N_CODE + (size_t)row * N_CODE;
        out[obase + j0] = x0;
        if (lane < 63) out[obase + j1] = x1;

        // cur-writes -> next-iter gathers: ordered by the in-order DS pipe.
        asm volatile("" ::: "memory");
        __builtin_amdgcn_sched_barrier(0);
    }
}

extern "C" void kernel_launch(void* const* d_in, const int* in_sizes, int n_in,
                              void* d_out, int out_size, void* d_ws, size_t ws_size,
                              hipStream_t stream) {
    const float* soft       = (const float*)d_in[0];
    const int*   labels     = (const int*)d_in[1];
    const int*   H          = (const int*)d_in[2];
    const float* normalizor = (const float*)d_in[3];
    float*       out        = (float*)d_out;

    nms_decode<<<BATCH / 4, 256, 0, stream>>>(soft, labels, H, normalizor, out);
}